// Round 5
// baseline (21.231 us; speedup 1.0000x reference)
//
#include <hip/hip_runtime.h>

// Fused Quanvolution + conv + FC + log_softmax via MFMA, MI355X (gfx950).
//
// Quantum features in closed form (Heisenberg-picture, verified R1-R4):
//   z0 = cos(x00); z1 = cos(x01); z2 = cos(x00)*cos(x10)
//   z3 = 0.5*((c1*c3 - s3) - c0*c2*(c1*c3 + s3))
//
// R5 vs R4 (20.7 us): kill address-divergent global loads.
//  - x staged to LDS per block (16 images, 50 KB) with coalesced float4
//    reads + ds_write_b128; padded image stride 788 words (3152 B) keeps
//    the per-lane b64 patch reads <=4-way bank-conflicted.
//  - fc_w B-fragments hoisted to registers (wave wid owns groups g=wid+8j,
//    j unrolled 0..6): 35 one-time loads replace 5 divergent loads/iter.
//  - MFMA mapping identical to R4 (refcheck-verified): lane=(img=l&15,
//    slot=l>>4); A k-slice = slot's patch, 8 feats; same permutation on A/B.

typedef _Float16 f16x8 __attribute__((ext_vector_type(8)));
typedef float    f32x4 __attribute__((ext_vector_type(4)));
typedef unsigned int u32x4 __attribute__((ext_vector_type(4)));

#define XSTRIDE 788  // words per image in LDS (784 + 4 pad)

__global__ __launch_bounds__(512, 4) void quanv_mfma(
    const float* __restrict__ x,       // [B][784]
    const float* __restrict__ conv_w,  // [4][1][2][2]
    const float* __restrict__ conv_b,  // [4]
    const float* __restrict__ fc_w,    // [10][1568]
    const float* __restrict__ fc_b,    // [10]
    float* __restrict__ out,           // [B][10]
    int B)
{
    __shared__ __align__(16) float xl[16 * XSTRIDE];  // 50.4 KB staged images
    __shared__ float red[8][16][16];                  // 8 KB wave partials

    const int tid  = threadIdx.x;
    const int wid  = tid >> 6;
    const int lane = tid & 63;
    const int l15  = lane & 15;        // A row (img) AND B col (o)
    const int slot = lane >> 4;        // k-slice = patch within 4-patch group
    const int b0   = blockIdx.x * 16;

    // ---- B-operand fragments: hoisted to registers (one-time loads) ----
    const int   o   = l15;
    const int   oc  = (o < 10) ? o : 9;
    const float msk = (o < 10) ? 1.f : 0.f;
    const float* wr = fc_w + oc * 1568;

    f16x8 bw[7];
#pragma unroll
    for (int j = 0; j < 7; ++j) {
        const int g = wid + (j << 3);
        if (g < 49) {
            const int p = (g << 2) + slot;
            const float w0 = wr[p]       * msk;
            const float w1 = wr[196 + p] * msk;
            const float w2 = wr[392 + p] * msk;
            const float w3 = wr[588 + p] * msk;
            const float4 wq = *reinterpret_cast<const float4*>(wr + 784 + p * 4);
            u32x4 wu;
            wu[0] = __builtin_bit_cast(unsigned int, __builtin_amdgcn_cvt_pkrtz(w0, w1));
            wu[1] = __builtin_bit_cast(unsigned int, __builtin_amdgcn_cvt_pkrtz(w2, w3));
            wu[2] = __builtin_bit_cast(unsigned int, __builtin_amdgcn_cvt_pkrtz(wq.x * msk, wq.y * msk));
            wu[3] = __builtin_bit_cast(unsigned int, __builtin_amdgcn_cvt_pkrtz(wq.z * msk, wq.w * msk));
            bw[j] = __builtin_bit_cast(f16x8, wu);
        } else {
            u32x4 z = {0u, 0u, 0u, 0u};
            bw[j] = __builtin_bit_cast(f16x8, z);
        }
    }

    // uniform conv tensors (uniform addresses -> scalar loads)
    float cw[16], cb[4];
#pragma unroll
    for (int i = 0; i < 16; ++i) cw[i] = conv_w[i];
#pragma unroll
    for (int i = 0; i < 4; ++i) cb[i] = conv_b[i];

    // ---- stage x: coalesced float4 global reads -> padded LDS images ----
    {
        const float* xg = x + (size_t)b0 * 784;
        for (int i = tid; i < 3136; i += 512) {        // 3136 = 16*784/4 vec4s
            const float4 v = *reinterpret_cast<const float4*>(xg + 4 * i);
            const int img = i / 196;                   // 196 vec4 per image
            const int w   = (i - img * 196) * 4;
            *reinterpret_cast<float4*>(&xl[img * XSTRIDE + w]) = v;
        }
    }
    __syncthreads();

    // ---- main loop: A from LDS, B from registers, one MFMA per group ----
    const float* xim = &xl[l15 * XSTRIDE];
    f32x4 acc = {0.f, 0.f, 0.f, 0.f};

#pragma unroll
    for (int j = 0; j < 7; ++j) {
        const int g = wid + (j << 3);
        if (g < 49) {
            const int p   = (g << 2) + slot;           // patch id < 196
            const int pi  = p / 14;
            const int pj  = p - pi * 14;
            const int off = pi * 56 + pj * 2;

            const float2 r0 = *reinterpret_cast<const float2*>(xim + off);
            const float2 r1 = *reinterpret_cast<const float2*>(xim + off + 28);
            const float x00 = r0.x, x01 = r0.y, x10 = r1.x, x11 = r1.y;

            const float ft0 = fmaf(x00, cw[0],  fmaf(x01, cw[1],  fmaf(x10, cw[2],  fmaf(x11, cw[3],  cb[0]))));
            const float ft1 = fmaf(x00, cw[4],  fmaf(x01, cw[5],  fmaf(x10, cw[6],  fmaf(x11, cw[7],  cb[1]))));
            const float ft2 = fmaf(x00, cw[8],  fmaf(x01, cw[9],  fmaf(x10, cw[10], fmaf(x11, cw[11], cb[2]))));
            const float ft3 = fmaf(x00, cw[12], fmaf(x01, cw[13], fmaf(x10, cw[14], fmaf(x11, cw[15], cb[3]))));

            const float c0 = __cosf(x00);
            const float c1 = __cosf(x01);
            const float c2 = __cosf(x10);
            const float s3 = __sinf(x11);
            const float c3 = __cosf(x11);
            const float t  = c0 * c2;                  // z2
            const float u  = c1 * c3;
            const float z3 = 0.5f * ((u - s3) - t * (u + s3));

            u32x4 au;
            au[0] = __builtin_bit_cast(unsigned int, __builtin_amdgcn_cvt_pkrtz(ft0, ft1));
            au[1] = __builtin_bit_cast(unsigned int, __builtin_amdgcn_cvt_pkrtz(ft2, ft3));
            au[2] = __builtin_bit_cast(unsigned int, __builtin_amdgcn_cvt_pkrtz(c0, c1));
            au[3] = __builtin_bit_cast(unsigned int, __builtin_amdgcn_cvt_pkrtz(t, z3));
            const f16x8 a = __builtin_bit_cast(f16x8, au);

            acc = __builtin_amdgcn_mfma_f32_16x16x32_f16(a, bw[j], acc, 0, 0, 0);
        }
    }

    // ---- partial C -> LDS: lane holds C[row=slot*4+r][col=l15] = [img][o]
#pragma unroll
    for (int r = 0; r < 4; ++r)
        red[wid][slot * 4 + r][l15] = acc[r];
    __syncthreads();

    // ---- sum 8 wave-partials: thread t owns cell (row=t>>4, col=t&15)
    if (tid < 256) {
        const int row = tid >> 4, col = tid & 15;
        float s = 0.f;
#pragma unroll
        for (int w = 0; w < 8; ++w) s += red[w][row][col];
        red[0][row][col] = s;
    }
    __syncthreads();

    // ---- log_softmax + store: thread im handles image b0+im ----
    if (tid < 16) {
        const int im = tid;
        if (b0 + im < B) {
            float lg[10];
#pragma unroll
            for (int j = 0; j < 10; ++j) lg[j] = red[0][im][j] + fc_b[j];
            float mx = lg[0];
#pragma unroll
            for (int j = 1; j < 10; ++j) mx = fmaxf(mx, lg[j]);
            float se = 0.f;
#pragma unroll
            for (int j = 0; j < 10; ++j) se += __expf(lg[j] - mx);
            const float lse = __logf(se) + mx;
            float* op = out + (size_t)(b0 + im) * 10;
#pragma unroll
            for (int j = 0; j < 10; ++j) op[j] = lg[j] - lse;
        }
    }
}

extern "C" void kernel_launch(void* const* d_in, const int* in_sizes, int n_in,
                              void* d_out, int out_size, void* d_ws, size_t ws_size,
                              hipStream_t stream) {
    const float* x      = (const float*)d_in[0];
    const float* conv_w = (const float*)d_in[1];
    const float* conv_b = (const float*)d_in[2];
    const float* fc_w   = (const float*)d_in[3];
    const float* fc_b   = (const float*)d_in[4];
    float* out = (float*)d_out;

    const int B = in_sizes[0] / 784;           // 8192
    const int blocks = (B + 15) / 16;          // 16 images per block
    quanv_mfma<<<blocks, 512, 0, stream>>>(x, conv_w, conv_b, fc_w, fc_b, out, B);
}

// Round 6
// 19.587 us; speedup vs baseline: 1.0839x; 1.0839x over previous
//
#include <hip/hip_runtime.h>

// Fused Quanvolution + conv + FC + log_softmax via MFMA, MI355X (gfx950).
//
// Quantum features in closed form (Heisenberg-picture, verified R1-R5):
//   z0 = cos(x00); z1 = cos(x01); z2 = cos(x00)*cos(x10)
//   z3 = 0.5*((c1*c3 - s3) - c0*c2*(c1*c3 + s3))
//
// R6 vs R5 (21.2 us): attack per-wave latency, not memory pattern (R4==R5
// proved loads don't matter).
//  - Software pipeline: ALL 14 pixel ds_read_b64 issued into registers first,
//    compute loop is pure-register afterwards (no LDS in the trig/MFMA chain).
//  - x staged PRESCALED by 1/(2pi); conv weights scaled by 2pi to compensate.
//    Trig becomes raw v_cos/v_sin (no per-use argument scaling): -5 insts/iter.
//  - z3's 0.5 folded into B-fragment slot 7: -1 inst/iter.
//  - Stage loads issued before B-prep so B-prep math hides global latency.
// MFMA mapping identical to R4/R5 (refcheck-verified): lane=(img=l&15,
// slot=l>>4); A k-slice = slot's patch, 8 feats; same permutation on A/B.

typedef _Float16 f16x8 __attribute__((ext_vector_type(8)));
typedef float    f32x4 __attribute__((ext_vector_type(4)));
typedef unsigned int u32x4 __attribute__((ext_vector_type(4)));

#define XSTRIDE 788  // words per image in LDS (784 + 4 pad)
#define INV2PI 0.15915494309189535f
#define TWOPI  6.283185307179586f

__global__ __launch_bounds__(512, 4) void quanv_mfma(
    const float* __restrict__ x,       // [B][784]
    const float* __restrict__ conv_w,  // [4][1][2][2]
    const float* __restrict__ conv_b,  // [4]
    const float* __restrict__ fc_w,    // [10][1568]
    const float* __restrict__ fc_b,    // [10]
    float* __restrict__ out,           // [B][10]
    int B)
{
    __shared__ __align__(16) float xl[16 * XSTRIDE];  // 50.4 KB prescaled imgs
    __shared__ float red[8][16][16];                  // 8 KB wave partials

    const int tid  = threadIdx.x;
    const int wid  = tid >> 6;
    const int lane = tid & 63;
    const int l15  = lane & 15;        // A row (img) AND B col (o)
    const int slot = lane >> 4;        // k-slice = patch within 4-patch group
    const int b0   = blockIdx.x * 16;

    // ---- phase 0: issue coalesced stage loads (latency hidden by B-prep) ----
    const float* xg = x + (size_t)b0 * 784;
    float4 sv[7];
#pragma unroll
    for (int c = 0; c < 7; ++c) {
        const int i = tid + (c << 9);
        if (c < 6 || i < 3136) sv[c] = *reinterpret_cast<const float4*>(xg + 4 * i);
    }

    // ---- phase 1: B-operand fragments (one-time divergent loads + pack) ----
    const int   o   = l15;
    const int   oc  = (o < 10) ? o : 9;
    const float msk = (o < 10) ? 1.f : 0.f;
    const float* wr = fc_w + oc * 1568;

    f16x8 bw[7];
#pragma unroll
    for (int j = 0; j < 7; ++j) {
        const int g = wid + (j << 3);
        if (g < 49) {
            const int p = (g << 2) + slot;
            const float w0 = wr[p]       * msk;
            const float w1 = wr[196 + p] * msk;
            const float w2 = wr[392 + p] * msk;
            const float w3 = wr[588 + p] * msk;
            const float4 wq = *reinterpret_cast<const float4*>(wr + 784 + p * 4);
            u32x4 wu;
            wu[0] = __builtin_bit_cast(unsigned int, __builtin_amdgcn_cvt_pkrtz(w0, w1));
            wu[1] = __builtin_bit_cast(unsigned int, __builtin_amdgcn_cvt_pkrtz(w2, w3));
            wu[2] = __builtin_bit_cast(unsigned int, __builtin_amdgcn_cvt_pkrtz(wq.x * msk, wq.y * msk));
            wu[3] = __builtin_bit_cast(unsigned int, __builtin_amdgcn_cvt_pkrtz(wq.z * msk, wq.w * (0.5f * msk)));
            bw[j] = __builtin_bit_cast(f16x8, wu);
        } else {
            u32x4 z = {0u, 0u, 0u, 0u};
            bw[j] = __builtin_bit_cast(f16x8, z);
        }
    }

    // uniform conv tensors -> scalar regs; fold 2pi (compensates prescale)
    float cw[16], cb[4];
#pragma unroll
    for (int i = 0; i < 16; ++i) cw[i] = conv_w[i] * TWOPI;
#pragma unroll
    for (int i = 0; i < 4; ++i) cb[i] = conv_b[i];

    // ---- phase 2: prescale + LDS write, barrier ----
#pragma unroll
    for (int c = 0; c < 7; ++c) {
        const int i = tid + (c << 9);
        if (c < 6 || i < 3136) {
            const int img = i / 196;
            const int w   = (i - img * 196) * 4;
            float4 v = sv[c];
            v.x *= INV2PI; v.y *= INV2PI; v.z *= INV2PI; v.w *= INV2PI;
            *reinterpret_cast<float4*>(&xl[img * XSTRIDE + w]) = v;
        }
    }
    __syncthreads();

    // ---- phase 3: ALL pixel loads into registers (back-to-back ds_reads) ----
    const float* xim = &xl[l15 * XSTRIDE];
    float2 pxa[7], pxb[7];
#pragma unroll
    for (int j = 0; j < 6; ++j) {
        const int p   = ((wid + (j << 3)) << 2) + slot;
        const int pi  = p / 14;
        const int pj  = p - pi * 14;
        const int off = pi * 56 + pj * 2;
        pxa[j] = *reinterpret_cast<const float2*>(xim + off);
        pxb[j] = *reinterpret_cast<const float2*>(xim + off + 28);
    }
    if (wid == 0) {                    // j=6 exists only for wave 0 (g=48)
        const int p   = 192 + slot;    // pi=13
        const int off = 13 * 56 + (p - 182) * 2;
        pxa[6] = *reinterpret_cast<const float2*>(xim + off);
        pxb[6] = *reinterpret_cast<const float2*>(xim + off + 28);
    }

    // ---- phase 4: pure-register compute loop ----
    f32x4 acc = {0.f, 0.f, 0.f, 0.f};

#define BODY(j)                                                                 \
    {                                                                           \
        const float x00 = pxa[j].x, x01 = pxa[j].y;                             \
        const float x10 = pxb[j].x, x11 = pxb[j].y;                             \
        const float ft0 = fmaf(x00, cw[0],  fmaf(x01, cw[1],  fmaf(x10, cw[2],  fmaf(x11, cw[3],  cb[0])))); \
        const float ft1 = fmaf(x00, cw[4],  fmaf(x01, cw[5],  fmaf(x10, cw[6],  fmaf(x11, cw[7],  cb[1])))); \
        const float ft2 = fmaf(x00, cw[8],  fmaf(x01, cw[9],  fmaf(x10, cw[10], fmaf(x11, cw[11], cb[2])))); \
        const float ft3 = fmaf(x00, cw[12], fmaf(x01, cw[13], fmaf(x10, cw[14], fmaf(x11, cw[15], cb[3])))); \
        const float c0 = __builtin_amdgcn_cosf(x00);                            \
        const float c1 = __builtin_amdgcn_cosf(x01);                            \
        const float c2 = __builtin_amdgcn_cosf(x10);                            \
        const float s3 = __builtin_amdgcn_sinf(x11);                            \
        const float c3 = __builtin_amdgcn_cosf(x11);                            \
        const float t  = c0 * c2;                                               \
        const float u  = c1 * c3;                                               \
        const float z3 = fmaf(-t, u + s3, u - s3); /* 0.5 folded into B */      \
        u32x4 au;                                                               \
        au[0] = __builtin_bit_cast(unsigned int, __builtin_amdgcn_cvt_pkrtz(ft0, ft1)); \
        au[1] = __builtin_bit_cast(unsigned int, __builtin_amdgcn_cvt_pkrtz(ft2, ft3)); \
        au[2] = __builtin_bit_cast(unsigned int, __builtin_amdgcn_cvt_pkrtz(c0, c1));   \
        au[3] = __builtin_bit_cast(unsigned int, __builtin_amdgcn_cvt_pkrtz(t, z3));    \
        acc = __builtin_amdgcn_mfma_f32_16x16x32_f16(__builtin_bit_cast(f16x8, au), bw[j], acc, 0, 0, 0); \
    }

    BODY(0) BODY(1) BODY(2) BODY(3) BODY(4) BODY(5)
    if (wid == 0) BODY(6)
#undef BODY

    // ---- partial C -> LDS: lane holds C[row=slot*4+r][col=l15] = [img][o]
#pragma unroll
    for (int r = 0; r < 4; ++r)
        red[wid][slot * 4 + r][l15] = acc[r];
    __syncthreads();

    // ---- sum 8 wave-partials: thread t owns cell (row=t>>4, col=t&15)
    if (tid < 256) {
        const int row = tid >> 4, col = tid & 15;
        float s = 0.f;
#pragma unroll
        for (int w = 0; w < 8; ++w) s += red[w][row][col];
        red[0][row][col] = s;
    }
    __syncthreads();

    // ---- log_softmax + store: thread im handles image b0+im ----
    if (tid < 16) {
        const int im = tid;
        if (b0 + im < B) {
            float lg[10];
#pragma unroll
            for (int j = 0; j < 10; ++j) lg[j] = red[0][im][j] + fc_b[j];
            float mx = lg[0];
#pragma unroll
            for (int j = 1; j < 10; ++j) mx = fmaxf(mx, lg[j]);
            float se = 0.f;
#pragma unroll
            for (int j = 0; j < 10; ++j) se += __expf(lg[j] - mx);
            const float lse = __logf(se) + mx;
            float* op = out + (size_t)(b0 + im) * 10;
#pragma unroll
            for (int j = 0; j < 10; ++j) op[j] = lg[j] - lse;
        }
    }
}

extern "C" void kernel_launch(void* const* d_in, const int* in_sizes, int n_in,
                              void* d_out, int out_size, void* d_ws, size_t ws_size,
                              hipStream_t stream) {
    const float* x      = (const float*)d_in[0];
    const float* conv_w = (const float*)d_in[1];
    const float* conv_b = (const float*)d_in[2];
    const float* fc_w   = (const float*)d_in[3];
    const float* fc_b   = (const float*)d_in[4];
    float* out = (float*)d_out;

    const int B = in_sizes[0] / 784;           // 8192
    const int blocks = (B + 15) / 16;          // 16 images per block
    quanv_mfma<<<blocks, 512, 0, stream>>>(x, conv_w, conv_b, fc_w, fc_b, out, B);
}